// Round 1
// baseline (721.494 us; speedup 1.0000x reference)
//
#include <hip/hip_runtime.h>

typedef __bf16 bf16x8 __attribute__((ext_vector_type(8)));
typedef float  f32x4  __attribute__((ext_vector_type(4)));

constexpr int kHW = 2304;   // 48*48
constexpr int kC  = 512;
constexpr int kB  = 16;

// ---------------------------------------------------------------------------
// K0: convert weights to bf16. Wqk [128][512] rows 0-63=Wq, 64-127=Wk. Wvb [512][512].
__global__ void pack_weights(const float* __restrict__ Wq, const float* __restrict__ Wk,
                             const float* __restrict__ Wv, __bf16* __restrict__ Wqk,
                             __bf16* __restrict__ Wvb) {
    int idx = blockIdx.x * 256 + threadIdx.x;      // 0 .. 262143 (grid 1024x256)
    if (idx < 64 * 512) {
        Wqk[idx]            = (__bf16)Wq[idx];
        Wqk[64 * 512 + idx] = (__bf16)Wk[idx];
    }
    if (idx < 512 * 512) Wvb[idx] = (__bf16)Wv[idx];
}

// ---------------------------------------------------------------------------
// K1: x [B][C][HW] fp32  ->  XT [B][HW][C] bf16  (64x64 LDS tile transpose)
__global__ void pack_x(const float* __restrict__ x, __bf16* __restrict__ XT) {
    __shared__ __bf16 tile[64][65];
    int b = blockIdx.z, c0 = blockIdx.y * 64, n0 = blockIdx.x * 64;
    int t = threadIdx.x;
    const float* xb = x + (size_t)b * kC * kHW;
#pragma unroll
    for (int rep = 0; rep < 16; ++rep) {
        int c_loc = rep * 4 + (t >> 6);
        int n_loc = t & 63;
        tile[c_loc][n_loc] = (__bf16)xb[(size_t)(c0 + c_loc) * kHW + n0 + n_loc];
    }
    __syncthreads();
    __bf16* XTb = XT + (size_t)b * kHW * kC;
#pragma unroll
    for (int rep = 0; rep < 16; ++rep) {
        int n_loc = rep * 4 + (t >> 6);
        int c_loc = t & 63;
        XTb[(size_t)(n0 + n_loc) * kC + c0 + c_loc] = tile[c_loc][n_loc];
    }
}

// ---------------------------------------------------------------------------
// K2: qkT [B*HW][128] = XT [B*HW][512] @ Wqk^T  (+bias).  D[row=n][col=o].
__global__ __launch_bounds__(256) void qk_gemm(const __bf16* __restrict__ XT,
                                               const __bf16* __restrict__ Wqk,
                                               const float* __restrict__ bq,
                                               const float* __restrict__ bk,
                                               __bf16* __restrict__ qkT) {
    int n0 = blockIdx.x * 128;
    int t = threadIdx.x, wave = t >> 6, lane = t & 63, quad = lane >> 4, l16 = lane & 15;
    f32x4 acc[8][2];
#pragma unroll
    for (int i = 0; i < 8; ++i)
#pragma unroll
        for (int j = 0; j < 2; ++j) acc[i][j] = (f32x4){0.f, 0.f, 0.f, 0.f};

    for (int k0 = 0; k0 < 512; k0 += 32) {
        bf16x8 bfr[2];
#pragma unroll
        for (int ct = 0; ct < 2; ++ct)
            bfr[ct] = *(const bf16x8*)(Wqk + (size_t)(wave * 32 + ct * 16 + l16) * 512 + k0 + quad * 8);
#pragma unroll
        for (int rt = 0; rt < 8; ++rt) {
            bf16x8 a = *(const bf16x8*)(XT + (size_t)(n0 + rt * 16 + l16) * 512 + k0 + quad * 8);
#pragma unroll
            for (int ct = 0; ct < 2; ++ct)
                acc[rt][ct] = __builtin_amdgcn_mfma_f32_16x16x32_bf16(a, bfr[ct], acc[rt][ct], 0, 0, 0);
        }
    }
#pragma unroll
    for (int ct = 0; ct < 2; ++ct) {
        int o = wave * 32 + ct * 16 + l16;
        float bias = (o < 64) ? bq[o] : bk[o - 64];
#pragma unroll
        for (int rt = 0; rt < 8; ++rt)
#pragma unroll
            for (int r = 0; r < 4; ++r) {
                int n = n0 + rt * 16 + quad * 4 + r;
                qkT[(size_t)n * 128 + o] = (__bf16)(acc[rt][ct][r] + bias);
            }
    }
}

// ---------------------------------------------------------------------------
// K3: v [b][c][m] = Wv [512][512] @ x_b  (+bv).  A=Wv rows(c), B=XT_b rows(m).
__global__ __launch_bounds__(256) void v_gemm(const __bf16* __restrict__ XT,
                                              const __bf16* __restrict__ Wvb,
                                              const float* __restrict__ bv,
                                              __bf16* __restrict__ vbuf) {
    int m0 = blockIdx.x * 128, c0 = blockIdx.y * 128, b = blockIdx.z;
    int t = threadIdx.x, wave = t >> 6, lane = t & 63, quad = lane >> 4, l16 = lane & 15;
    const __bf16* XTb = XT + (size_t)b * kHW * kC;
    f32x4 acc[8][2];
#pragma unroll
    for (int i = 0; i < 8; ++i)
#pragma unroll
        for (int j = 0; j < 2; ++j) acc[i][j] = (f32x4){0.f, 0.f, 0.f, 0.f};

    for (int k0 = 0; k0 < 512; k0 += 32) {
        bf16x8 bfr[2];
#pragma unroll
        for (int ct = 0; ct < 2; ++ct)
            bfr[ct] = *(const bf16x8*)(XTb + (size_t)(m0 + wave * 32 + ct * 16 + l16) * 512 + k0 + quad * 8);
#pragma unroll
        for (int rt = 0; rt < 8; ++rt) {
            bf16x8 a = *(const bf16x8*)(Wvb + (size_t)(c0 + rt * 16 + l16) * 512 + k0 + quad * 8);
#pragma unroll
            for (int ct = 0; ct < 2; ++ct)
                acc[rt][ct] = __builtin_amdgcn_mfma_f32_16x16x32_bf16(a, bfr[ct], acc[rt][ct], 0, 0, 0);
        }
    }
#pragma unroll
    for (int rt = 0; rt < 8; ++rt)
#pragma unroll
        for (int r = 0; r < 4; ++r) {
            int c = c0 + rt * 16 + quad * 4 + r;
            float bias = bv[c];
#pragma unroll
            for (int ct = 0; ct < 2; ++ct) {
                int m = m0 + wave * 32 + ct * 16 + l16;
                vbuf[((size_t)b * kC + c) * kHW + m] = (__bf16)(acc[rt][ct][r] + bias);
            }
        }
}

// ---------------------------------------------------------------------------
// K4: flash attention (no max subtraction — logits are small) + epilogue.
// block = (b, 128-row n-block, 256-col c-half); Tm = 64.
__global__ __launch_bounds__(256, 2) void attn_kernel(const __bf16* __restrict__ qkT,
                                                      const __bf16* __restrict__ vbuf,
                                                      const float* __restrict__ x,
                                                      const float* __restrict__ gamma,
                                                      float* __restrict__ out) {
    __shared__ __align__(16) __bf16 P_lds[128 * 72];   // +8 pad: stride 144 B, conflict-free
    __shared__ __align__(16) __bf16 V_lds[256 * 72];
    __shared__ float rs_lds[128];

    int n0 = blockIdx.x * 128, c0 = blockIdx.y * 256, b = blockIdx.z;
    int t = threadIdx.x, wave = t >> 6, lane = t & 63, quad = lane >> 4, l16 = lane & 15;
    const __bf16* qkT_b = qkT + (size_t)b * kHW * 128;
    const __bf16* v_b   = vbuf + (size_t)b * kC * kHW;

    // Q fragments live in registers across the whole m-loop (wave owns rows 32*wave..+31)
    bf16x8 aq[2][2];
#pragma unroll
    for (int rt2 = 0; rt2 < 2; ++rt2)
#pragma unroll
        for (int dk = 0; dk < 2; ++dk)
            aq[rt2][dk] = *(const bf16x8*)(qkT_b +
                (size_t)(n0 + (wave * 2 + rt2) * 16 + l16) * 128 + dk * 32 + quad * 8);

    f32x4 acc[8][4];
#pragma unroll
    for (int i = 0; i < 8; ++i)
#pragma unroll
        for (int j = 0; j < 4; ++j) acc[i][j] = (f32x4){0.f, 0.f, 0.f, 0.f};
    float rowsum = 0.f;

    for (int m0 = 0; m0 < kHW; m0 += 64) {
        // stage V tile [256 c][64 m] -> LDS (coalesced 16B)
#pragma unroll
        for (int rep = 0; rep < 8; ++rep) {
            int idx = rep * 256 + t;
            int c_loc = idx >> 3, seg = idx & 7;
            bf16x8 tv = *(const bf16x8*)(v_b + (size_t)(c0 + c_loc) * kHW + m0 + seg * 8);
            *(bf16x8*)(&V_lds[c_loc * 72 + seg * 8]) = tv;
        }
        // phase 1: S = Q K_tile, P = exp(S) -> LDS. wave owns rows 32*wave..+31.
#pragma unroll
        for (int rt2 = 0; rt2 < 2; ++rt2) {
            int row_base = (wave * 2 + rt2) * 16 + quad * 4;
#pragma unroll
            for (int mt = 0; mt < 4; ++mt) {
                f32x4 s = (f32x4){0.f, 0.f, 0.f, 0.f};
#pragma unroll
                for (int dk = 0; dk < 2; ++dk) {
                    bf16x8 bk8 = *(const bf16x8*)(qkT_b +
                        (size_t)(m0 + mt * 16 + l16) * 128 + 64 + dk * 32 + quad * 8);
                    s = __builtin_amdgcn_mfma_f32_16x16x32_bf16(aq[rt2][dk], bk8, s, 0, 0, 0);
                }
#pragma unroll
                for (int r = 0; r < 4; ++r) {
                    float p = __expf(s[r]);
                    P_lds[(row_base + r) * 72 + mt * 16 + l16] = (__bf16)p;
                }
            }
        }
        __syncthreads();
        // rowsum over the bf16 P actually used by the MFMAs (keeps the ratio consistent)
        if (t < 128) {
            float rs = 0.f;
#pragma unroll
            for (int i = 0; i < 8; ++i) {
                bf16x8 pv = *(const bf16x8*)(&P_lds[t * 72 + i * 8]);
#pragma unroll
                for (int j = 0; j < 8; ++j) rs += (float)pv[j];
            }
            rowsum += rs;
        }
        // phase 2: O += P @ V^T. wave owns cols 64*wave..+63, all 128 rows.
#pragma unroll
        for (int dk = 0; dk < 2; ++dk) {
            bf16x8 bfr[4];
#pragma unroll
            for (int ct = 0; ct < 4; ++ct)
                bfr[ct] = *(const bf16x8*)(&V_lds[(wave * 64 + ct * 16 + l16) * 72 + dk * 32 + quad * 8]);
#pragma unroll
            for (int rt = 0; rt < 8; ++rt) {
                bf16x8 a = *(const bf16x8*)(&P_lds[(rt * 16 + l16) * 72 + dk * 32 + quad * 8]);
#pragma unroll
                for (int ct = 0; ct < 4; ++ct)
                    acc[rt][ct] = __builtin_amdgcn_mfma_f32_16x16x32_bf16(a, bfr[ct], acc[rt][ct], 0, 0, 0);
            }
        }
        __syncthreads();
    }

    if (t < 128) rs_lds[t] = rowsum;
    __syncthreads();

    float g = gamma[0];
    const float* x_b = x + (size_t)b * kC * kHW;
    float* out_b = out + (size_t)b * kC * kHW;
#pragma unroll
    for (int rt = 0; rt < 8; ++rt) {
        float inv[4];
#pragma unroll
        for (int r = 0; r < 4; ++r) inv[r] = 1.f / rs_lds[rt * 16 + quad * 4 + r];
#pragma unroll
        for (int ct = 0; ct < 4; ++ct) {
            int c = c0 + wave * 64 + ct * 16 + l16;
            size_t base = (size_t)c * kHW + n0 + rt * 16 + quad * 4;   // 4 consecutive n
            f32x4 xin = *(const f32x4*)(x_b + base);
            f32x4 y;
#pragma unroll
            for (int r = 0; r < 4; ++r) y[r] = g * acc[rt][ct][r] * inv[r] + xin[r];
            *(f32x4*)(out_b + base) = y;
        }
    }
}

// ---------------------------------------------------------------------------
extern "C" void kernel_launch(void* const* d_in, const int* in_sizes, int n_in,
                              void* d_out, int out_size, void* d_ws, size_t ws_size,
                              hipStream_t stream) {
    const float* x     = (const float*)d_in[0];
    const float* Wq    = (const float*)d_in[1];
    const float* bq    = (const float*)d_in[2];
    const float* Wk    = (const float*)d_in[3];
    const float* bk    = (const float*)d_in[4];
    const float* Wv    = (const float*)d_in[5];
    const float* bv    = (const float*)d_in[6];
    const float* gamma = (const float*)d_in[7];
    float* out = (float*)d_out;

    char* ws = (char*)d_ws;
    __bf16* XT   = (__bf16*)(ws);                 // 16*2304*512*2  = 37,748,736
    __bf16* Wqk  = (__bf16*)(ws + 37748736);      // 128*512*2     =    131,072
    __bf16* Wvb  = (__bf16*)(ws + 37879808);      // 512*512*2     =    524,288
    __bf16* qkT  = (__bf16*)(ws + 38404096);      // 16*2304*128*2 =  9,437,184
    __bf16* vbuf = (__bf16*)(ws + 47841280);      // 16*512*2304*2 = 37,748,736
    // total = 85,590,016 bytes

    hipLaunchKernelGGL(pack_weights, dim3(1024), dim3(256), 0, stream, Wq, Wk, Wv, Wqk, Wvb);
    hipLaunchKernelGGL(pack_x, dim3(36, 8, 16), dim3(256), 0, stream, x, XT);
    hipLaunchKernelGGL(qk_gemm, dim3(288), dim3(256), 0, stream, XT, Wqk, bq, bk, qkT);
    hipLaunchKernelGGL(v_gemm, dim3(18, 4, 16), dim3(256), 0, stream, XT, Wvb, bv, vbuf);
    hipLaunchKernelGGL(attn_kernel, dim3(18, 2, 16), dim3(256), 0, stream, qkT, vbuf, x, gamma, out);
}

// Round 2
// 705.732 us; speedup vs baseline: 1.0223x; 1.0223x over previous
//
#include <hip/hip_runtime.h>

typedef __bf16 bf16x8 __attribute__((ext_vector_type(8)));
typedef float  f32x4  __attribute__((ext_vector_type(4)));

constexpr int kHW = 2304;   // 48*48
constexpr int kC  = 512;

// ---------------------------------------------------------------------------
// K0: convert weights to bf16. Wqk [128][512] rows 0-63=Wq, 64-127=Wk. Wvb [512][512].
__global__ void pack_weights(const float* __restrict__ Wq, const float* __restrict__ Wk,
                             const float* __restrict__ Wv, __bf16* __restrict__ Wqk,
                             __bf16* __restrict__ Wvb) {
    int idx = blockIdx.x * 256 + threadIdx.x;      // 0 .. 262143 (grid 1024x256)
    if (idx < 64 * 512) {
        Wqk[idx]            = (__bf16)Wq[idx];
        Wqk[64 * 512 + idx] = (__bf16)Wk[idx];
    }
    if (idx < 512 * 512) Wvb[idx] = (__bf16)Wv[idx];
}

// ---------------------------------------------------------------------------
// K1: x [B][C][HW] fp32  ->  XT [B][HW][C] bf16  (64x64 LDS tile transpose)
__global__ void pack_x(const float* __restrict__ x, __bf16* __restrict__ XT) {
    __shared__ __bf16 tile[64][65];
    int b = blockIdx.z, c0 = blockIdx.y * 64, n0 = blockIdx.x * 64;
    int t = threadIdx.x;
    const float* xb = x + (size_t)b * kC * kHW;
#pragma unroll
    for (int rep = 0; rep < 16; ++rep) {
        int c_loc = rep * 4 + (t >> 6);
        int n_loc = t & 63;
        tile[c_loc][n_loc] = (__bf16)xb[(size_t)(c0 + c_loc) * kHW + n0 + n_loc];
    }
    __syncthreads();
    __bf16* XTb = XT + (size_t)b * kHW * kC;
#pragma unroll
    for (int rep = 0; rep < 16; ++rep) {
        int n_loc = rep * 4 + (t >> 6);
        int c_loc = t & 63;
        XTb[(size_t)(n0 + n_loc) * kC + c0 + c_loc] = tile[c_loc][n_loc];
    }
}

// ---------------------------------------------------------------------------
// K2: merged QKV projection.
//  colblk 0:  qkT[n][128] = XT_b @ Wqk^T + bias   (A=XT rows n, B=Wqk rows o)
//  colblk>=1: vbuf[c][m]  = Wvb @ XT_b^T + bv     (A=Wvb rows c, B=XT rows m)
__global__ __launch_bounds__(256) void qkv_gemm(const __bf16* __restrict__ XT,
                                                const __bf16* __restrict__ Wqk,
                                                const __bf16* __restrict__ Wvb,
                                                const float* __restrict__ bq,
                                                const float* __restrict__ bk,
                                                const float* __restrict__ bv,
                                                __bf16* __restrict__ qkT,
                                                __bf16* __restrict__ vbuf) {
    int r0 = blockIdx.x * 128;           // n (qk) or m (v)
    int colblk = blockIdx.y;
    int b = blockIdx.z;
    int t = threadIdx.x, wave = t >> 6, lane = t & 63, quad = lane >> 4, l16 = lane & 15;
    const __bf16* XTb = XT + (size_t)b * kHW * kC;
    const __bf16* A_base;
    const __bf16* B_base;
    if (colblk == 0) { A_base = XTb + (size_t)r0 * kC; B_base = Wqk; }
    else             { A_base = Wvb + (size_t)(colblk - 1) * 128 * kC; B_base = XTb + (size_t)r0 * kC; }

    f32x4 acc[8][2];
#pragma unroll
    for (int i = 0; i < 8; ++i)
#pragma unroll
        for (int j = 0; j < 2; ++j) acc[i][j] = (f32x4){0.f, 0.f, 0.f, 0.f};

    for (int k0 = 0; k0 < 512; k0 += 32) {
        bf16x8 bfr[2];
#pragma unroll
        for (int ct = 0; ct < 2; ++ct)
            bfr[ct] = *(const bf16x8*)(B_base + (size_t)(wave * 32 + ct * 16 + l16) * 512 + k0 + quad * 8);
#pragma unroll
        for (int rt = 0; rt < 8; ++rt) {
            bf16x8 a = *(const bf16x8*)(A_base + (size_t)(rt * 16 + l16) * 512 + k0 + quad * 8);
#pragma unroll
            for (int ct = 0; ct < 2; ++ct)
                acc[rt][ct] = __builtin_amdgcn_mfma_f32_16x16x32_bf16(a, bfr[ct], acc[rt][ct], 0, 0, 0);
        }
    }

    if (colblk == 0) {
#pragma unroll
        for (int ct = 0; ct < 2; ++ct) {
            int o = wave * 32 + ct * 16 + l16;
            float bias = (o < 64) ? bq[o] : bk[o - 64];
#pragma unroll
            for (int rt = 0; rt < 8; ++rt)
#pragma unroll
                for (int r = 0; r < 4; ++r) {
                    int n = r0 + rt * 16 + quad * 4 + r;
                    qkT[((size_t)b * kHW + n) * 128 + o] = (__bf16)(acc[rt][ct][r] + bias);
                }
        }
    } else {
#pragma unroll
        for (int rt = 0; rt < 8; ++rt)
#pragma unroll
            for (int r = 0; r < 4; ++r) {
                int c = (colblk - 1) * 128 + rt * 16 + quad * 4 + r;
                float bias = bv[c];
#pragma unroll
                for (int ct = 0; ct < 2; ++ct) {
                    int m = r0 + wave * 32 + ct * 16 + l16;
                    vbuf[((size_t)b * kC + c) * kHW + m] = (__bf16)(acc[rt][ct][r] + bias);
                }
            }
    }
}

// ---------------------------------------------------------------------------
// K3: flash attention, n-tile 64, c-tile 128 per block, V direct from global,
// double-buffered P in LDS (one barrier per m-iter), per-lane rowsum + shfl.
__global__ __launch_bounds__(256, 4) void attn_kernel(const __bf16* __restrict__ qkT,
                                                      const __bf16* __restrict__ vbuf,
                                                      const float* __restrict__ x,
                                                      const float* __restrict__ gamma,
                                                      float* __restrict__ out) {
    __shared__ __align__(16) __bf16 P_lds[2][64 * 72];   // 144B rows: b128-aligned
    __shared__ float rs_lds[64];

    int n0 = blockIdx.x * 64, c0 = blockIdx.y * 128, b = blockIdx.z;
    int t = threadIdx.x, wave = t >> 6, lane = t & 63, quad = lane >> 4, l16 = lane & 15;
    const __bf16* qkT_b = qkT + (size_t)b * kHW * 128;
    const __bf16* v_b   = vbuf + (size_t)b * kC * kHW;

    // Q fragments: wave owns rows n0+wave*16 .. +15 (A layout: row=l16, k=quad*8+j)
    bf16x8 aq[2];
#pragma unroll
    for (int dk = 0; dk < 2; ++dk)
        aq[dk] = *(const bf16x8*)(qkT_b + (size_t)(n0 + wave * 16 + l16) * 128 + dk * 32 + quad * 8);

    f32x4 acc[4][2];
#pragma unroll
    for (int i = 0; i < 4; ++i)
#pragma unroll
        for (int j = 0; j < 2; ++j) acc[i][j] = (f32x4){0.f, 0.f, 0.f, 0.f};
    float rsum[4] = {0.f, 0.f, 0.f, 0.f};

    // phase1: S = Q @ K_tile^T for rows wave*16..+15, P=exp(S) -> P_lds[buf]
    auto phase1 = [&](int m0, int buf) {
#pragma unroll
        for (int mt = 0; mt < 4; ++mt) {
            f32x4 s = (f32x4){0.f, 0.f, 0.f, 0.f};
#pragma unroll
            for (int dk = 0; dk < 2; ++dk) {
                bf16x8 bk8 = *(const bf16x8*)(qkT_b +
                    (size_t)(m0 + mt * 16 + l16) * 128 + 64 + dk * 32 + quad * 8);
                s = __builtin_amdgcn_mfma_f32_16x16x32_bf16(aq[dk], bk8, s, 0, 0, 0);
            }
#pragma unroll
            for (int r = 0; r < 4; ++r) {
                __bf16 pb = (__bf16)__expf(s[r]);
                rsum[r] += (float)pb;
                P_lds[buf][(wave * 16 + quad * 4 + r) * 72 + mt * 16 + l16] = pb;
            }
        }
    };

    phase1(0, 0);
    __syncthreads();

    for (int i = 0; i < 36; ++i) {
        int m0 = i * 64, buf = i & 1;
        // phase2: O += P @ V^T (V fragments straight from global; L2-resident)
#pragma unroll
        for (int dk = 0; dk < 2; ++dk) {
            bf16x8 vfr[2];
#pragma unroll
            for (int ct = 0; ct < 2; ++ct)
                vfr[ct] = *(const bf16x8*)(v_b +
                    (size_t)(c0 + wave * 32 + ct * 16 + l16) * kHW + m0 + dk * 32 + quad * 8);
            bf16x8 afr[4];
#pragma unroll
            for (int rt = 0; rt < 4; ++rt)
                afr[rt] = *(const bf16x8*)(&P_lds[buf][(rt * 16 + l16) * 72 + dk * 32 + quad * 8]);
#pragma unroll
            for (int rt = 0; rt < 4; ++rt)
#pragma unroll
                for (int ct = 0; ct < 2; ++ct)
                    acc[rt][ct] = __builtin_amdgcn_mfma_f32_16x16x32_bf16(afr[rt], vfr[ct], acc[rt][ct], 0, 0, 0);
        }
        if (i + 1 < 36) phase1((i + 1) * 64, buf ^ 1);
        __syncthreads();
    }

    // rowsum: reduce over the 16 l16-lanes (rows are per (wave,quad,r))
#pragma unroll
    for (int r = 0; r < 4; ++r) {
        float v = rsum[r];
        v += __shfl_xor(v, 1);
        v += __shfl_xor(v, 2);
        v += __shfl_xor(v, 4);
        v += __shfl_xor(v, 8);
        if (l16 == 0) rs_lds[wave * 16 + quad * 4 + r] = v;
    }
    __syncthreads();

    float g = gamma[0];
    const float* x_b = x + (size_t)b * kC * kHW;
    float* out_b = out + (size_t)b * kC * kHW;
#pragma unroll
    for (int rt = 0; rt < 4; ++rt) {
        float inv[4];
#pragma unroll
        for (int r = 0; r < 4; ++r) inv[r] = 1.f / rs_lds[rt * 16 + quad * 4 + r];
#pragma unroll
        for (int ct = 0; ct < 2; ++ct) {
            int c = c0 + wave * 32 + ct * 16 + l16;
            size_t base = (size_t)c * kHW + n0 + rt * 16 + quad * 4;   // 4 consecutive n
            f32x4 xin = *(const f32x4*)(x_b + base);
            f32x4 y;
#pragma unroll
            for (int r = 0; r < 4; ++r) y[r] = g * acc[rt][ct][r] * inv[r] + xin[r];
            *(f32x4*)(out_b + base) = y;
        }
    }
}

// ---------------------------------------------------------------------------
extern "C" void kernel_launch(void* const* d_in, const int* in_sizes, int n_in,
                              void* d_out, int out_size, void* d_ws, size_t ws_size,
                              hipStream_t stream) {
    const float* x     = (const float*)d_in[0];
    const float* Wq    = (const float*)d_in[1];
    const float* bq    = (const float*)d_in[2];
    const float* Wk    = (const float*)d_in[3];
    const float* bk    = (const float*)d_in[4];
    const float* Wv    = (const float*)d_in[5];
    const float* bv    = (const float*)d_in[6];
    const float* gamma = (const float*)d_in[7];
    float* out = (float*)d_out;

    char* ws = (char*)d_ws;
    __bf16* XT   = (__bf16*)(ws);                 // 16*2304*512*2  = 37,748,736
    __bf16* Wqk  = (__bf16*)(ws + 37748736);      // 128*512*2     =    131,072
    __bf16* Wvb  = (__bf16*)(ws + 37879808);      // 512*512*2     =    524,288
    __bf16* qkT  = (__bf16*)(ws + 38404096);      // 16*2304*128*2 =  9,437,184
    __bf16* vbuf = (__bf16*)(ws + 47841280);      // 16*512*2304*2 = 37,748,736
    // total = 85,590,016 bytes

    hipLaunchKernelGGL(pack_weights, dim3(1024), dim3(256), 0, stream, Wq, Wk, Wv, Wqk, Wvb);
    hipLaunchKernelGGL(pack_x, dim3(36, 8, 16), dim3(256), 0, stream, x, XT);
    hipLaunchKernelGGL(qkv_gemm, dim3(18, 5, 16), dim3(256), 0, stream,
                       XT, Wqk, Wvb, bq, bk, bv, qkT, vbuf);
    hipLaunchKernelGGL(attn_kernel, dim3(36, 4, 16), dim3(256), 0, stream,
                       qkT, vbuf, x, gamma, out);
}

// Round 4
// 410.692 us; speedup vs baseline: 1.7568x; 1.7184x over previous
//
#include <hip/hip_runtime.h>

typedef __bf16 bf16x8 __attribute__((ext_vector_type(8)));
typedef float  f32x4  __attribute__((ext_vector_type(4)));

constexpr int kHW = 2304;   // 48*48
constexpr int kC  = 512;

// async global->LDS, 16B per lane. gptr per-lane (base + lane*16B), lptr wave-uniform chunk base.
__device__ __forceinline__ void dma16(const __bf16* g, __bf16* l) {
    __builtin_amdgcn_global_load_lds(
        (const volatile __attribute__((address_space(1))) void*)g,
        (volatile __attribute__((address_space(3))) void*)l, 16, 0, 0);
}

// ---------------------------------------------------------------------------
// K0: weights -> bf16, padded tile-major layouts.
// Wqk2 [kblk=8][128 o][72], Wvb2 [kblk=8][512 c][72]  (cols 64..71 = unused pad)
__global__ void pack_weights(const float* __restrict__ Wq, const float* __restrict__ Wk,
                             const float* __restrict__ Wv, __bf16* __restrict__ Wqk2,
                             __bf16* __restrict__ Wvb2) {
    int idx = blockIdx.x * 256 + threadIdx.x;    // grid 1024 -> 262144
    int o = idx >> 9, k = idx & 511, kb = k >> 6, kr = k & 63;
    if (idx < 64 * 512) {
        Wqk2[((size_t)kb * 128 + o) * 72 + kr]      = (__bf16)Wq[idx];
        Wqk2[((size_t)kb * 128 + 64 + o) * 72 + kr] = (__bf16)Wk[idx];
    }
    if (idx < 512 * 512)
        Wvb2[((size_t)kb * 512 + o) * 72 + kr] = (__bf16)Wv[idx];
}

// ---------------------------------------------------------------------------
// K1: x [B][C][HW] fp32 -> XT2 [b][kblk=8][2304 n][72] bf16 (c-inner, padded rows)
__global__ void pack_x(const float* __restrict__ x, __bf16* __restrict__ XT2) {
    __shared__ __bf16 tile[64][65];              // [c][n]
    int n0 = blockIdx.x * 64, kblk = blockIdx.y, b = blockIdx.z;
    int c0 = kblk * 64;
    int t = threadIdx.x;
    const float* xb = x + (size_t)b * kC * kHW;
#pragma unroll
    for (int rep = 0; rep < 16; ++rep) {
        int c_loc = rep * 4 + (t >> 6);
        int n_loc = t & 63;
        tile[c_loc][n_loc] = (__bf16)xb[(size_t)(c0 + c_loc) * kHW + n0 + n_loc];
    }
    __syncthreads();
    __bf16* dst = XT2 + ((size_t)b * 8 + kblk) * kHW * 72;
#pragma unroll
    for (int rep = 0; rep < 2; ++rep) {
        int item = rep * 256 + t;                // 512 items = 64 n x 8 chunks
        int n_loc = item >> 3, chunk = item & 7;
        bf16x8 v;
#pragma unroll
        for (int j = 0; j < 8; ++j) v[j] = tile[chunk * 8 + j][n_loc];
        *(bf16x8*)(dst + (size_t)(n0 + n_loc) * 72 + chunk * 8) = v;
    }
}

// ---------------------------------------------------------------------------
// K2: QKV projections, m97-style: DMA-staged LDS tiles, BK=64, 2 barriers/iter.
//  type 0:  rows n (A=XT2), cols o (B=Wqk2) -> qbuf [b][n][64] / kbuf [b][mblk][64][72]
//  type>=1: rows c (A=Wvb2), cols m (B=XT2) -> vbuf2 [b][mblk][512][72]
__global__ __launch_bounds__(256) void qkv_gemm(const __bf16* __restrict__ XT2,
                                                const __bf16* __restrict__ Wqk2,
                                                const __bf16* __restrict__ Wvb2,
                                                const float* __restrict__ bq,
                                                const float* __restrict__ bk,
                                                const float* __restrict__ bv,
                                                __bf16* __restrict__ qbuf,
                                                __bf16* __restrict__ kbuf,
                                                __bf16* __restrict__ vbuf2) {
    __shared__ __align__(16) __bf16 A_lds[128 * 72];
    __shared__ __align__(16) __bf16 B_lds[128 * 72];
    int r0 = blockIdx.x * 128, type = blockIdx.y, b = blockIdx.z;
    int t = threadIdx.x, wave = t >> 6, lane = t & 63, quad = lane >> 4, l16 = lane & 15;

    f32x4 acc[8][2];
#pragma unroll
    for (int i = 0; i < 8; ++i)
#pragma unroll
        for (int j = 0; j < 2; ++j) acc[i][j] = (f32x4){0.f, 0.f, 0.f, 0.f};

    for (int kb = 0; kb < 8; ++kb) {
        const __bf16* Asrc;
        const __bf16* Bsrc;
        if (type == 0) {
            Asrc = XT2 + (((size_t)b * 8 + kb) * kHW + r0) * 72;
            Bsrc = Wqk2 + (size_t)kb * 128 * 72;
        } else {
            Asrc = Wvb2 + ((size_t)kb * 512 + (type - 1) * 128) * 72;
            Bsrc = XT2 + (((size_t)b * 8 + kb) * kHW + r0) * 72;
        }
        __syncthreads();                          // previous iter's LDS reads done
        for (int ch = wave; ch < 18; ch += 4) {   // 18 KB per matrix, 1KB/call
            dma16(Asrc + ch * 512 + lane * 8, &A_lds[ch * 512]);
            dma16(Bsrc + ch * 512 + lane * 8, &B_lds[ch * 512]);
        }
        __syncthreads();                          // DMA complete
#pragma unroll
        for (int dk = 0; dk < 2; ++dk) {
            bf16x8 bfr[2];
#pragma unroll
            for (int ct = 0; ct < 2; ++ct)
                bfr[ct] = *(const bf16x8*)(&B_lds[(wave * 32 + ct * 16 + l16) * 72 + dk * 32 + quad * 8]);
#pragma unroll
            for (int rt = 0; rt < 8; ++rt) {
                bf16x8 a = *(const bf16x8*)(&A_lds[(rt * 16 + l16) * 72 + dk * 32 + quad * 8]);
#pragma unroll
                for (int ct = 0; ct < 2; ++ct)
                    acc[rt][ct] = __builtin_amdgcn_mfma_f32_16x16x32_bf16(a, bfr[ct], acc[rt][ct], 0, 0, 0);
            }
        }
    }

    if (type == 0) {
#pragma unroll
        for (int ct = 0; ct < 2; ++ct) {
            int o = wave * 32 + ct * 16 + l16;
            float bias = (o < 64) ? bq[o] : bk[o - 64];
#pragma unroll
            for (int rt = 0; rt < 8; ++rt)
#pragma unroll
                for (int r = 0; r < 4; ++r) {
                    int n = r0 + rt * 16 + quad * 4 + r;
                    __bf16 val = (__bf16)(acc[rt][ct][r] + bias);
                    if (o < 64)
                        qbuf[((size_t)b * kHW + n) * 64 + o] = val;
                    else
                        kbuf[(((size_t)b * 36 + (n >> 6)) * 64 + (n & 63)) * 72 + (o - 64)] = val;
                }
        }
    } else {
#pragma unroll
        for (int rt = 0; rt < 8; ++rt)
#pragma unroll
            for (int r = 0; r < 4; ++r) {
                int c = (type - 1) * 128 + rt * 16 + quad * 4 + r;
                float bias = bv[c];
#pragma unroll
                for (int ct = 0; ct < 2; ++ct) {
                    int m = r0 + wave * 32 + ct * 16 + l16;
                    vbuf2[(((size_t)b * 36 + (m >> 6)) * 512 + c) * 72 + (m & 63)] = (__bf16)(acc[rt][ct][r] + bias);
                }
            }
    }
}

// ---------------------------------------------------------------------------
// K3: flash attention, n128 x c128 tile, Tm=64.
// K/V LDS are DOUBLE-BUFFERED: DMA(i+1) -> buf^1 is issued immediately after
// the top barrier of iter i (all waves are past their buf^1 reads from iter
// i-1), and is drained by each wave's own vmcnt wait at the next top barrier
// (the m97-verified mechanism). No DMA ever targets a live buffer.
__global__ __launch_bounds__(256, 2) void attn_kernel(const __bf16* __restrict__ qbuf,
                                                      const __bf16* __restrict__ kbuf,
                                                      const __bf16* __restrict__ vbuf2,
                                                      const float* __restrict__ x,
                                                      const float* __restrict__ gamma,
                                                      float* __restrict__ out) {
    __shared__ __align__(16) __bf16 K_lds[2][64 * 72];    // 18.0 KB
    __shared__ __align__(16) __bf16 V_lds[2][128 * 72];   // 36.0 KB
    __shared__ __align__(16) __bf16 P_lds[128 * 72];      // 18.0 KB
    __shared__ float rs_lds[128];

    int n0 = blockIdx.x * 128, c0 = blockIdx.y * 128, b = blockIdx.z;
    int t = threadIdx.x, wave = t >> 6, lane = t & 63, quad = lane >> 4, l16 = lane & 15;
    const __bf16* q_b    = qbuf + (size_t)b * kHW * 64;
    const __bf16* k_base = kbuf + (size_t)b * 36 * 64 * 72;

    // Q fragments (held all kernel): wave owns S rows 32*wave .. +31
    bf16x8 aq[2][2];
#pragma unroll
    for (int rt2 = 0; rt2 < 2; ++rt2)
#pragma unroll
        for (int dk = 0; dk < 2; ++dk)
            aq[rt2][dk] = *(const bf16x8*)(q_b + (size_t)(n0 + wave * 32 + rt2 * 16 + l16) * 64 + dk * 32 + quad * 8);

    f32x4 acc[8][2];
#pragma unroll
    for (int i = 0; i < 8; ++i)
#pragma unroll
        for (int j = 0; j < 2; ++j) acc[i][j] = (f32x4){0.f, 0.f, 0.f, 0.f};
    float rsum[2][4] = {{0.f, 0.f, 0.f, 0.f}, {0.f, 0.f, 0.f, 0.f}};

    auto issue_dma = [&](int i, int buf) {
        const __bf16* ks = k_base + (size_t)i * 64 * 72;
        const __bf16* vs = vbuf2 + (((size_t)b * 36 + i) * 512 + c0) * 72;
        for (int ch = wave; ch < 9; ch += 4)
            dma16(ks + ch * 512 + lane * 8, &K_lds[buf][ch * 512]);
        for (int ch = wave; ch < 18; ch += 4)
            dma16(vs + ch * 512 + lane * 8, &V_lds[buf][ch * 512]);
    };

    issue_dma(0, 0);
    for (int i = 0; i < 36; ++i) {
        int buf = i & 1;
        __syncthreads();        // DMA(i) drained; all iter i-1 LDS reads done; P(i-1) consumed
        if (i + 1 < 36) issue_dma(i + 1, buf ^ 1);   // into the idle buffer
        // V fragments -> regs
        bf16x8 vfrag[2][2];
#pragma unroll
        for (int ct = 0; ct < 2; ++ct)
#pragma unroll
            for (int dk = 0; dk < 2; ++dk)
                vfrag[ct][dk] = *(const bf16x8*)(&V_lds[buf][(wave * 32 + ct * 16 + l16) * 72 + dk * 32 + quad * 8]);
        // phase 1: S = Q @ K_tile^T (rows 32w..+31), P = exp(S) -> LDS
#pragma unroll
        for (int mt = 0; mt < 4; ++mt) {
            bf16x8 kf0 = *(const bf16x8*)(&K_lds[buf][(mt * 16 + l16) * 72 + quad * 8]);
            bf16x8 kf1 = *(const bf16x8*)(&K_lds[buf][(mt * 16 + l16) * 72 + 32 + quad * 8]);
#pragma unroll
            for (int rt2 = 0; rt2 < 2; ++rt2) {
                f32x4 s = (f32x4){0.f, 0.f, 0.f, 0.f};
                s = __builtin_amdgcn_mfma_f32_16x16x32_bf16(aq[rt2][0], kf0, s, 0, 0, 0);
                s = __builtin_amdgcn_mfma_f32_16x16x32_bf16(aq[rt2][1], kf1, s, 0, 0, 0);
#pragma unroll
                for (int r = 0; r < 4; ++r) {
                    __bf16 pb = (__bf16)__expf(s[r]);
                    rsum[rt2][r] += (float)pb;
                    P_lds[(wave * 32 + rt2 * 16 + quad * 4 + r) * 72 + mt * 16 + l16] = pb;
                }
            }
        }
        __syncthreads();        // P visible
        // phase 2: O += P @ V^T  (wave owns c-cols 32w..+31, all 128 rows)
#pragma unroll
        for (int dk = 0; dk < 2; ++dk)
#pragma unroll
            for (int rt = 0; rt < 8; ++rt) {
                bf16x8 pf = *(const bf16x8*)(&P_lds[(rt * 16 + l16) * 72 + dk * 32 + quad * 8]);
                acc[rt][0] = __builtin_amdgcn_mfma_f32_16x16x32_bf16(pf, vfrag[0][dk], acc[rt][0], 0, 0, 0);
                acc[rt][1] = __builtin_amdgcn_mfma_f32_16x16x32_bf16(pf, vfrag[1][dk], acc[rt][1], 0, 0, 0);
            }
    }

    // rowsum reduce over l16 lanes -> rs_lds
#pragma unroll
    for (int rt2 = 0; rt2 < 2; ++rt2)
#pragma unroll
        for (int r = 0; r < 4; ++r) {
            float v = rsum[rt2][r];
            v += __shfl_xor(v, 1);
            v += __shfl_xor(v, 2);
            v += __shfl_xor(v, 4);
            v += __shfl_xor(v, 8);
            if (l16 == 0) rs_lds[wave * 32 + rt2 * 16 + quad * 4 + r] = v;
        }
    __syncthreads();

    float g = gamma[0];
    const float* x_b = x + (size_t)b * kC * kHW;
    float* out_b = out + (size_t)b * kC * kHW;
#pragma unroll
    for (int rt = 0; rt < 8; ++rt) {
        float inv[4];
#pragma unroll
        for (int r = 0; r < 4; ++r) inv[r] = 1.f / rs_lds[rt * 16 + quad * 4 + r];
#pragma unroll
        for (int ct = 0; ct < 2; ++ct) {
            int c = c0 + wave * 32 + ct * 16 + l16;
            size_t base = (size_t)c * kHW + n0 + rt * 16 + quad * 4;
            f32x4 xin = *(const f32x4*)(x_b + base);
            f32x4 y;
#pragma unroll
            for (int r = 0; r < 4; ++r) y[r] = g * acc[rt][ct][r] * inv[r] + xin[r];
            *(f32x4*)(out_b + base) = y;
        }
    }
}

// ---------------------------------------------------------------------------
extern "C" void kernel_launch(void* const* d_in, const int* in_sizes, int n_in,
                              void* d_out, int out_size, void* d_ws, size_t ws_size,
                              hipStream_t stream) {
    const float* x     = (const float*)d_in[0];
    const float* Wq    = (const float*)d_in[1];
    const float* bq    = (const float*)d_in[2];
    const float* Wk    = (const float*)d_in[3];
    const float* bk    = (const float*)d_in[4];
    const float* Wv    = (const float*)d_in[5];
    const float* bv    = (const float*)d_in[6];
    const float* gamma = (const float*)d_in[7];
    float* out = (float*)d_out;

    char* ws = (char*)d_ws;
    __bf16* XT2   = (__bf16*)(ws);                 // 16*8*2304*72*2 = 42,467,328
    __bf16* Wqk2  = (__bf16*)(ws + 42467328);      // 8*128*72*2    =    147,456
    __bf16* Wvb2  = (__bf16*)(ws + 42614784);      // 8*512*72*2    =    589,824
    __bf16* qbuf  = (__bf16*)(ws + 43204608);      // 16*2304*64*2  =  4,718,592
    __bf16* kbuf  = (__bf16*)(ws + 47923200);      // 16*36*64*72*2 =  5,308,416
    __bf16* vbuf2 = (__bf16*)(ws + 53231616);      // 16*36*512*72*2= 42,467,328
    // total = 95,698,944 bytes

    hipLaunchKernelGGL(pack_weights, dim3(1024), dim3(256), 0, stream, Wq, Wk, Wv, Wqk2, Wvb2);
    hipLaunchKernelGGL(pack_x, dim3(36, 8, 16), dim3(256), 0, stream, x, XT2);
    hipLaunchKernelGGL(qkv_gemm, dim3(18, 5, 16), dim3(256), 0, stream,
                       XT2, Wqk2, Wvb2, bq, bk, bv, qbuf, kbuf, vbuf2);
    hipLaunchKernelGGL(attn_kernel, dim3(18, 4, 16), dim3(256), 0, stream,
                       qbuf, kbuf, vbuf2, x, gamma, out);
}